// Round 1
// baseline (4347.228 us; speedup 1.0000x reference)
//
#include <hip/hip_runtime.h>
#include <math.h>

// Problem constants (fixed by the reference)
constexpr int DIMc = 768;
constexpr int Hc   = 16;
constexpr int DHc  = 48;
constexpr int Bc   = 8;
constexpr int Sc   = 1024;
constexpr int NROW = Bc * Sc;          // 8192 flattened (b,s) rows
constexpr float INV_SCALE = 0.03608439182435161f;  // 1 / sqrt(768)

// ---------------------------------------------------------------------------
// Kernel A: fused per-head QKV projection.
// grid = (NROW/64, H), block = 256.
// Each block: 64 (b,s)-rows x one head x all three of Q,K,V (144 out cols).
// Thread t: row = t>>2, col-group = t&3 (12 cols per W).
// ---------------------------------------------------------------------------
__global__ __launch_bounds__(256) void qkv_proj_kernel(
    const float* __restrict__ x,
    const float* __restrict__ Wq, const float* __restrict__ bq,
    const float* __restrict__ Wk, const float* __restrict__ bk,
    const float* __restrict__ Wv, const float* __restrict__ bv,
    float* __restrict__ Qo, float* __restrict__ Ko, float* __restrict__ Vo)
{
    const int rt = blockIdx.x;
    const int h  = blockIdx.y;

    __shared__ float Xs[64][33];     // 64 rows x 32 k, pad 33 (conflict-free)
    __shared__ float Ws[32][148];    // 32 k x (48 Q | 48 K | 48 V), stride 148 -> 592B rows (16B aligned)

    const int t   = threadIdx.x;
    const int row = t >> 2;
    const int cg  = t & 3;
    const int c0  = cg * 12;
    const int row0 = rt * 64;

    float acc[36];
    #pragma unroll
    for (int i = 0; i < 36; ++i) acc[i] = 0.f;

    for (int k0 = 0; k0 < DIMc; k0 += 32) {
        __syncthreads();
        // load X tile 64x32 (coalesced, 8 elems/thread)
        #pragma unroll
        for (int i = 0; i < 8; ++i) {
            int idx = t + i * 256;
            Xs[idx >> 5][idx & 31] =
                x[(size_t)(row0 + (idx >> 5)) * DIMc + k0 + (idx & 31)];
        }
        // load W tiles 32x48 for Q,K,V (6 elems/thread each)
        #pragma unroll
        for (int i = 0; i < 6; ++i) {
            int idx = t + i * 256;
            int kk = idx / 48, e = idx % 48;
            size_t off = ((size_t)h * DIMc + k0 + kk) * DHc + e;
            Ws[kk][e]      = Wq[off];
            Ws[kk][48 + e] = Wk[off];
            Ws[kk][96 + e] = Wv[off];
        }
        __syncthreads();

        #pragma unroll
        for (int kk = 0; kk < 32; ++kk) {
            const float xv = Xs[row][kk];
            const float4* wrow = reinterpret_cast<const float4*>(&Ws[kk][0]);
            #pragma unroll
            for (int w = 0; w < 3; ++w) {
                float4 a = wrow[w * 12 + 3 * cg + 0];
                float4 b = wrow[w * 12 + 3 * cg + 1];
                float4 c = wrow[w * 12 + 3 * cg + 2];
                float* A = &acc[w * 12];
                A[0]  += xv * a.x; A[1]  += xv * a.y; A[2]  += xv * a.z; A[3]  += xv * a.w;
                A[4]  += xv * b.x; A[5]  += xv * b.y; A[6]  += xv * b.z; A[7]  += xv * b.w;
                A[8]  += xv * c.x; A[9]  += xv * c.y; A[10] += xv * c.z; A[11] += xv * c.w;
            }
        }
    }

    const int grow = row0 + row;
    const int b = grow >> 10;        // /1024
    const int s = grow & 1023;
    const size_t base = ((size_t)(b * Hc + h) * Sc + s) * DHc + c0;
    #pragma unroll
    for (int c = 0; c < 12; ++c) {
        Qo[base + c] = acc[c]      + bq[h * DHc + c0 + c];
        Ko[base + c] = acc[12 + c] + bk[h * DHc + c0 + c];
        Vo[base + c] = acc[24 + c] + bv[h * DHc + c0 + c];
    }
}

// ---------------------------------------------------------------------------
// Kernel B: flash-style attention over one (b, h, 64-query tile).
// grid = (S/64, H, B), block = 256.
// Thread t: query row r = t>>2 within tile; key-group kg = t&3 (16 keys).
// Online softmax state (m, l) replicated across the 4 lanes of a row and
// kept consistent via width-4 shuffle reductions. P is shared via __shfl
// (no LDS round-trip, no extra barriers).
// ---------------------------------------------------------------------------
__global__ __launch_bounds__(256) void attn_kernel(
    const float* __restrict__ Q, const float* __restrict__ K,
    const float* __restrict__ V, float* __restrict__ AO)
{
    const int qt = blockIdx.x;
    const int h  = blockIdx.y;
    const int b  = blockIdx.z;

    __shared__ float Qs[64][52];   // stride 52 floats = 208B (16B aligned rows)
    __shared__ float Ks[64][52];
    __shared__ float Vs[64][52];

    const int t  = threadIdx.x;
    const int r  = t >> 2;
    const int kg = t & 3;

    const size_t bh = (size_t)(b * Hc + h) * Sc;
    const float* Qb = Q + bh * DHc;
    const float* Kb = K + bh * DHc;
    const float* Vb = V + bh * DHc;

    // cooperative Q tile load (12 elems/thread)
    #pragma unroll
    for (int i = 0; i < 12; ++i) {
        int idx = t + i * 256;
        int rr = idx / 48, e = idx % 48;
        Qs[rr][e] = Qb[(size_t)(qt * 64 + rr) * DHc + e];
    }
    __syncthreads();

    // own query row into registers
    float q[48];
    {
        const float4* qrow = reinterpret_cast<const float4*>(&Qs[r][0]);
        #pragma unroll
        for (int i = 0; i < 12; ++i) {
            float4 v = qrow[i];
            q[4*i+0] = v.x; q[4*i+1] = v.y; q[4*i+2] = v.z; q[4*i+3] = v.w;
        }
    }

    float m = -3.0e38f, l = 0.f;
    float acc[12];
    #pragma unroll
    for (int i = 0; i < 12; ++i) acc[i] = 0.f;

    for (int t0 = 0; t0 < Sc; t0 += 64) {
        __syncthreads();   // previous tile's Ks/Vs readers done
        #pragma unroll
        for (int i = 0; i < 12; ++i) {
            int idx = t + i * 256;
            int rr = idx / 48, e = idx % 48;
            Ks[rr][e] = Kb[(size_t)(t0 + rr) * DHc + e];
            Vs[rr][e] = Vb[(size_t)(t0 + rr) * DHc + e];
        }
        __syncthreads();

        // scores for my row x my 16 keys
        float sc[16];
        float smax = -3.0e38f;
        #pragma unroll
        for (int j = 0; j < 16; ++j) {
            const int k = kg * 16 + j;
            const float4* krow = reinterpret_cast<const float4*>(&Ks[k][0]);
            float d0 = 0.f, d1 = 0.f, d2 = 0.f, d3 = 0.f;
            #pragma unroll
            for (int e = 0; e < 12; ++e) {
                float4 kv = krow[e];
                d0 += q[4*e+0] * kv.x;
                d1 += q[4*e+1] * kv.y;
                d2 += q[4*e+2] * kv.z;
                d3 += q[4*e+3] * kv.w;
            }
            const float s = ((d0 + d1) + (d2 + d3)) * INV_SCALE;
            sc[j] = s;
            smax = fmaxf(smax, s);
        }
        // row max across the 4 lanes of this row
        smax = fmaxf(smax, __shfl_xor(smax, 1, 4));
        smax = fmaxf(smax, __shfl_xor(smax, 2, 4));

        const float newm = fmaxf(m, smax);
        const float corr = __expf(m - newm);
        float psum = 0.f;
        #pragma unroll
        for (int j = 0; j < 16; ++j) {
            sc[j] = __expf(sc[j] - newm);
            psum += sc[j];
        }
        psum += __shfl_xor(psum, 1, 4);
        psum += __shfl_xor(psum, 2, 4);
        l = l * corr + psum;
        m = newm;
        #pragma unroll
        for (int c = 0; c < 12; ++c) acc[c] *= corr;

        // PV: share P across the row's 4 lanes via width-4 shuffle
        #pragma unroll
        for (int ks = 0; ks < 4; ++ks) {
            #pragma unroll
            for (int j = 0; j < 16; ++j) {
                const float p = __shfl(sc[j], ks, 4);
                const int k = ks * 16 + j;
                const float4* vrow =
                    reinterpret_cast<const float4*>(&Vs[k][kg * 12]);
                float4 v0 = vrow[0], v1 = vrow[1], v2 = vrow[2];
                acc[0]  += p * v0.x; acc[1]  += p * v0.y;
                acc[2]  += p * v0.z; acc[3]  += p * v0.w;
                acc[4]  += p * v1.x; acc[5]  += p * v1.y;
                acc[6]  += p * v1.z; acc[7]  += p * v1.w;
                acc[8]  += p * v2.x; acc[9]  += p * v2.y;
                acc[10] += p * v2.z; acc[11] += p * v2.w;
            }
        }
    }

    const float invl = 1.0f / l;
    const int srow = qt * 64 + r;
    // write attn output in [b][s][h*DH+e] layout (heads already concatenated)
    float* o = AO + ((size_t)(b * Sc + srow)) * DIMc + h * DHc + kg * 12;
    #pragma unroll
    for (int c = 0; c < 12; ++c) o[c] = acc[c] * invl;
}

// ---------------------------------------------------------------------------
// Kernel C: output projection  out = AO[8192,768] @ Wp[768,768] + bp.
// grid = (NROW/64, DIM/64), block = 256. Thread: row = t>>2, 16 cols.
// ---------------------------------------------------------------------------
__global__ __launch_bounds__(256) void out_proj_kernel(
    const float* __restrict__ A, const float* __restrict__ Wp,
    const float* __restrict__ bp, float* __restrict__ out)
{
    const int rt = blockIdx.x, ct = blockIdx.y;

    __shared__ float As[64][33];
    __shared__ float Ws[32][68];   // stride 68 floats = 272B (16B aligned rows)

    const int t  = threadIdx.x;
    const int r  = t >> 2;
    const int cg = t & 3;
    const int row0 = rt * 64, col0 = ct * 64;

    float acc[16];
    #pragma unroll
    for (int i = 0; i < 16; ++i) acc[i] = 0.f;

    for (int k0 = 0; k0 < DIMc; k0 += 32) {
        __syncthreads();
        #pragma unroll
        for (int i = 0; i < 8; ++i) {
            int idx = t + i * 256;
            As[idx >> 5][idx & 31] =
                A[(size_t)(row0 + (idx >> 5)) * DIMc + k0 + (idx & 31)];
            Ws[idx >> 6][idx & 63] =
                Wp[(size_t)(k0 + (idx >> 6)) * DIMc + col0 + (idx & 63)];
        }
        __syncthreads();

        #pragma unroll
        for (int kk = 0; kk < 32; ++kk) {
            const float av = As[r][kk];
            const float4* wrow = reinterpret_cast<const float4*>(&Ws[kk][0]);
            float4 w0 = wrow[cg * 4 + 0];
            float4 w1 = wrow[cg * 4 + 1];
            float4 w2 = wrow[cg * 4 + 2];
            float4 w3 = wrow[cg * 4 + 3];
            acc[0]  += av * w0.x; acc[1]  += av * w0.y;
            acc[2]  += av * w0.z; acc[3]  += av * w0.w;
            acc[4]  += av * w1.x; acc[5]  += av * w1.y;
            acc[6]  += av * w1.z; acc[7]  += av * w1.w;
            acc[8]  += av * w2.x; acc[9]  += av * w2.y;
            acc[10] += av * w2.z; acc[11] += av * w2.w;
            acc[12] += av * w3.x; acc[13] += av * w3.y;
            acc[14] += av * w3.z; acc[15] += av * w3.w;
        }
    }

    const size_t orow = (size_t)(row0 + r) * DIMc + col0 + cg * 16;
    #pragma unroll
    for (int c = 0; c < 16; ++c)
        out[orow + c] = acc[c] + bp[col0 + cg * 16 + c];
}

// ---------------------------------------------------------------------------
extern "C" void kernel_launch(void* const* d_in, const int* in_sizes, int n_in,
                              void* d_out, int out_size, void* d_ws, size_t ws_size,
                              hipStream_t stream)
{
    (void)in_sizes; (void)n_in; (void)out_size; (void)ws_size;

    const float* x  = (const float*)d_in[0];
    const float* Wq = (const float*)d_in[1];
    const float* bq = (const float*)d_in[2];
    const float* Wk = (const float*)d_in[3];
    const float* bk = (const float*)d_in[4];
    const float* Wv = (const float*)d_in[5];
    const float* bv = (const float*)d_in[6];
    const float* Wp = (const float*)d_in[7];
    const float* bp = (const float*)d_in[8];
    float* out = (float*)d_out;
    float* ws  = (float*)d_ws;

    // workspace layout: Q | K | V (each [B,H,S,DH]) | AO ([B,S,DIM]) = ~101 MB
    const size_t QSZ = (size_t)Bc * Hc * Sc * DHc;   // 6291456 floats
    float* Qb = ws;
    float* Kb = ws + QSZ;
    float* Vb = ws + 2 * QSZ;
    float* AO = ws + 3 * QSZ;

    qkv_proj_kernel<<<dim3(NROW / 64, Hc), 256, 0, stream>>>(
        x, Wq, bq, Wk, bk, Wv, bv, Qb, Kb, Vb);
    attn_kernel<<<dim3(Sc / 64, Hc, Bc), 256, 0, stream>>>(Qb, Kb, Vb, AO);
    out_proj_kernel<<<dim3(NROW / 64, DIMc / 64), 256, 0, stream>>>(
        AO, Wp, bp, out);
}

// Round 5
// 740.357 us; speedup vs baseline: 5.8718x; 5.8718x over previous
//
#include <hip/hip_runtime.h>
#include <math.h>

constexpr int DIMc = 768;
constexpr int Hc   = 16;
constexpr int DHc  = 48;
constexpr int Bc   = 8;
constexpr int Sc   = 1024;
constexpr int NROW = Bc * Sc;                      // 8192
constexpr int NQKV = 3 * Hc * DHc;                 // 2304 fused output cols
constexpr float INV_SCALE = 0.03608439182435161f;  // 1/sqrt(768)

typedef short bf16x8 __attribute__((ext_vector_type(8)));
typedef float f32x4  __attribute__((ext_vector_type(4)));

// RNE float->bf16 (matches JAX conversion semantics for normal values)
__device__ inline ushort f2bf(float f) {
    uint u = __float_as_uint(f);
    uint r = (u + 0x7fffu + ((u >> 16) & 1u)) >> 16;
    return (ushort)r;
}

__device__ inline void gload_lds16(const void* g, void* l) {
    __builtin_amdgcn_global_load_lds(
        (const __attribute__((address_space(1))) void*)g,
        (__attribute__((address_space(3))) void*)l, 16, 0, 0);
}

// ---------------------------------------------------------------------------
// cvt_x: x[8192][768] f32 -> xb bf16 (same layout). 4 elems/thread.
// ---------------------------------------------------------------------------
__global__ __launch_bounds__(256) void cvt_x(
    const float* __restrict__ x, ushort* __restrict__ xb)
{
    const int i = (blockIdx.x * 256 + threadIdx.x) * 4;
    float4 v = *(const float4*)&x[i];
    ushort4 o;
    o.x = f2bf(v.x); o.y = f2bf(v.y); o.z = f2bf(v.z); o.w = f2bf(v.w);
    *(ushort4*)&xb[i] = o;
}

// ---------------------------------------------------------------------------
// cvt_w: build WbT[n=2304][k=768] bf16 (n = h*144 + m*48 + e, m in {q,k,v})
//        + fused bias bcomb[2304] f32. One thread per (n,k).
// ---------------------------------------------------------------------------
__global__ __launch_bounds__(256) void cvt_w(
    const float* __restrict__ Wq, const float* __restrict__ bq,
    const float* __restrict__ Wk, const float* __restrict__ bk,
    const float* __restrict__ Wv, const float* __restrict__ bv,
    ushort* __restrict__ WbT, float* __restrict__ bcomb)
{
    const int id = blockIdx.x * 256 + threadIdx.x;   // n*768 + k
    const int n = id / DIMc;
    const int k = id - n * DIMc;
    const int h = n / 144;
    const int rem = n - h * 144;
    const int m = rem / DHc;
    const int e = rem - m * DHc;
    const float* W = (m == 0) ? Wq : (m == 1) ? Wk : Wv;
    const float* bias = (m == 0) ? bq : (m == 1) ? bk : bv;
    WbT[(size_t)n * DIMc + k] = f2bf(W[((size_t)h * DIMc + k) * DHc + e]);
    if (k == 0) bcomb[n] = bias[h * DHc + e];
}

// ---------------------------------------------------------------------------
// Kernel A: fused QKV projection, bf16 MFMA (m97-structure).
// C[8192, 2304] = xb @ WbT^T, scattered to Q/K/V [B,H,S,DH] f32 + bias.
// grid = (18, 64) = (N-tiles, M-tiles); block = 256 (4 waves, 2x2).
// Tile 128x128, BK=32. Per wave: 4x4 frags of mfma_f32_16x16x32_bf16.
// Staging: global_load_lds width 16, linear LDS [row][32] bf16.
// ---------------------------------------------------------------------------
__global__ __launch_bounds__(256) void qkv_mfma(
    const ushort* __restrict__ xb, const ushort* __restrict__ WbT,
    const float* __restrict__ bcomb,
    float* __restrict__ Qo, float* __restrict__ Ko, float* __restrict__ Vo)
{
    __shared__ __align__(16) ushort Abuf[128 * 32];
    __shared__ __align__(16) ushort Bbuf[128 * 32];

    const int t    = threadIdx.x;
    const int lane = t & 63;
    const int wid  = t >> 6;
    const int wrow = wid >> 1;          // 0..1
    const int wcol = wid & 1;           // 0..1
    const int l15  = lane & 15;
    const int l16  = lane >> 4;         // k-chunk 0..3
    const int row0 = blockIdx.y * 128;
    const int col0 = blockIdx.x * 128;

    f32x4 acc[4][4];
    #pragma unroll
    for (int i = 0; i < 4; ++i)
        #pragma unroll
        for (int j = 0; j < 4; ++j)
            acc[i][j] = (f32x4){0.f, 0.f, 0.f, 0.f};

    for (int k0 = 0; k0 < DIMc; k0 += 32) {
        __syncthreads();   // previous tile's readers done
        // stage A and B tiles: 512 chunks x 16B each, 2 issues/thread/tile
        #pragma unroll
        for (int j = 0; j < 2; ++j) {
            const int c = j * 256 + t;           // chunk id; row=c>>2, kc=c&3
            gload_lds16(xb + (size_t)(row0 + (c >> 2)) * DIMc + k0 + (c & 3) * 8,
                        &Abuf[(size_t)c * 8]);
            gload_lds16(WbT + (size_t)(col0 + (c >> 2)) * DIMc + k0 + (c & 3) * 8,
                        &Bbuf[(size_t)c * 8]);
        }
        __syncthreads();   // compiler drains vmcnt before barrier

        bf16x8 af[4], bfr[4];
        #pragma unroll
        for (int i = 0; i < 4; ++i) {
            af[i]  = *(const bf16x8*)((const char*)Abuf +
                       ((wrow * 64 + i * 16 + l15) * 64 + l16 * 16));
            bfr[i] = *(const bf16x8*)((const char*)Bbuf +
                       ((wcol * 64 + i * 16 + l15) * 64 + l16 * 16));
        }
        #pragma unroll
        for (int i = 0; i < 4; ++i)
            #pragma unroll
            for (int j = 0; j < 4; ++j)
                acc[i][j] = __builtin_amdgcn_mfma_f32_16x16x32_bf16(
                    af[i], bfr[j], acc[i][j], 0, 0, 0);
    }

    // epilogue: C/D layout col=lane&15, row=(lane>>4)*4+reg (m89-verified)
    #pragma unroll
    for (int i = 0; i < 4; ++i) {
        const int grow0 = row0 + wrow * 64 + i * 16 + l16 * 4;
        #pragma unroll
        for (int j = 0; j < 4; ++j) {
            const int n = col0 + wcol * 64 + j * 16 + l15;
            const int h = n / 144;
            const int rem = n - h * 144;
            const int m = rem / DHc;
            const int e = rem - m * DHc;
            float* O = (m == 0) ? Qo : (m == 1) ? Ko : Vo;
            const float bias = bcomb[n];
            #pragma unroll
            for (int r = 0; r < 4; ++r) {
                const int grow = grow0 + r;
                const int b_ = grow >> 10;
                const int s  = grow & 1023;
                O[((size_t)(b_ * Hc + h) * Sc + s) * DHc + e] = acc[i][j][r] + bias;
            }
        }
    }
}

// ---------------------------------------------------------------------------
// Kernel B: flash attention, register-tiled fp32 (audited, unchanged).
// grid = (S/64, H, B), block = 256.
// ---------------------------------------------------------------------------
__global__ __launch_bounds__(256, 2) void attn_kernel(
    const float* __restrict__ Q, const float* __restrict__ K,
    const float* __restrict__ V, float* __restrict__ AO)
{
    const int qt = blockIdx.x;
    const int h  = blockIdx.y;
    const int b  = blockIdx.z;

    __shared__ float Qst[48][68];   // [dh][q] transposed
    __shared__ float Kst[48][68];   // [dh][k] transposed
    __shared__ float Vs[64][52];    // [k][e]
    __shared__ float Ps[64][68];    // [q][k]

    const int t  = threadIdx.x;
    const int rg = t >> 4;          // score rows 4rg..+3
    const int cg = t & 15;          // score cols 4cg..+3
    const int qg = t >> 3;          // pv rows 2qg, 2qg+1
    const int eg = t & 7;           // pv cols 6eg..+5
    const bool hi = (t >> 3) & 1;

    const size_t bh = ((size_t)b * Hc + h) * Sc;
    const float* Qb = Q + bh * DHc;
    const float* Kb = K + bh * DHc;
    const float* Vb = V + bh * DHc;

    #pragma unroll
    for (int i = 0; i < 3; ++i) {
        const int jj = t + i * 256;
        const int q  = jj / 12;
        const int ec = jj % 12;
        float4 v = *(const float4*)&Qb[(size_t)(qt * 64 + q) * DHc + ec * 4];
        Qst[ec * 4 + 0][q] = v.x;
        Qst[ec * 4 + 1][q] = v.y;
        Qst[ec * 4 + 2][q] = v.z;
        Qst[ec * 4 + 3][q] = v.w;
    }

    float m_[4], l_[4];
    #pragma unroll
    for (int i = 0; i < 4; ++i) { m_[i] = -3.0e38f; l_[i] = 0.f; }
    float accA[6], accB[6];
    #pragma unroll
    for (int j = 0; j < 6; ++j) { accA[j] = 0.f; accB[j] = 0.f; }

    for (int t0 = 0; t0 < Sc; t0 += 64) {
        __syncthreads();
        #pragma unroll
        for (int i = 0; i < 3; ++i) {
            const int jj = t + i * 256;
            const int k  = jj / 12;
            const int ec = jj % 12;
            float4 v = *(const float4*)&Kb[(size_t)(t0 + k) * DHc + ec * 4];
            Kst[ec * 4 + 0][k] = v.x;
            Kst[ec * 4 + 1][k] = v.y;
            Kst[ec * 4 + 2][k] = v.z;
            Kst[ec * 4 + 3][k] = v.w;
            float4 w = *(const float4*)&Vb[(size_t)(t0 + k) * DHc + ec * 4];
            *(float4*)&Vs[k][ec * 4] = w;
        }
        __syncthreads();

        float sc[4][4];
        #pragma unroll
        for (int i = 0; i < 4; ++i)
            #pragma unroll
            for (int j = 0; j < 4; ++j) sc[i][j] = 0.f;

        #pragma unroll 12
        for (int kk = 0; kk < 48; ++kk) {
            float4 qv = *(const float4*)&Qst[kk][rg * 4];
            float4 kv = *(const float4*)&Kst[kk][cg * 4];
            sc[0][0] += qv.x * kv.x; sc[0][1] += qv.x * kv.y;
            sc[0][2] += qv.x * kv.z; sc[0][3] += qv.x * kv.w;
            sc[1][0] += qv.y * kv.x; sc[1][1] += qv.y * kv.y;
            sc[1][2] += qv.y * kv.z; sc[1][3] += qv.y * kv.w;
            sc[2][0] += qv.z * kv.x; sc[2][1] += qv.z * kv.y;
            sc[2][2] += qv.z * kv.z; sc[2][3] += qv.z * kv.w;
            sc[3][0] += qv.w * kv.x; sc[3][1] += qv.w * kv.y;
            sc[3][2] += qv.w * kv.z; sc[3][3] += qv.w * kv.w;
        }

        float corr[4];
        #pragma unroll
        for (int i = 0; i < 4; ++i) {
            #pragma unroll
            for (int j = 0; j < 4; ++j) sc[i][j] *= INV_SCALE;
            float mx = fmaxf(fmaxf(sc[i][0], sc[i][1]), fmaxf(sc[i][2], sc[i][3]));
            mx = fmaxf(mx, __shfl_xor(mx, 1, 16));
            mx = fmaxf(mx, __shfl_xor(mx, 2, 16));
            mx = fmaxf(mx, __shfl_xor(mx, 4, 16));
            mx = fmaxf(mx, __shfl_xor(mx, 8, 16));
            const float newm = fmaxf(m_[i], mx);
            corr[i] = __expf(m_[i] - newm);
            float ps = 0.f;
            #pragma unroll
            for (int j = 0; j < 4; ++j) {
                sc[i][j] = __expf(sc[i][j] - newm);
                ps += sc[i][j];
            }
            ps += __shfl_xor(ps, 1, 16);
            ps += __shfl_xor(ps, 2, 16);
            ps += __shfl_xor(ps, 4, 16);
            ps += __shfl_xor(ps, 8, 16);
            l_[i] = l_[i] * corr[i] + ps;
            m_[i] = newm;
        }

        const float cA = hi ? corr[2] : corr[0];
        const float cB = hi ? corr[3] : corr[1];
        #pragma unroll
        for (int j = 0; j < 6; ++j) { accA[j] *= cA; accB[j] *= cB; }

        #pragma unroll
        for (int i = 0; i < 4; ++i) {
            float4 pv = make_float4(sc[i][0], sc[i][1], sc[i][2], sc[i][3]);
            *(float4*)&Ps[rg * 4 + i][cg * 4] = pv;
        }
        __syncthreads();

        #pragma unroll 16
        for (int kk = 0; kk < 64; ++kk) {
            const float pA = Ps[2 * qg][kk];
            const float pB = Ps[2 * qg + 1][kk];
            float2 v0 = *(const float2*)&Vs[kk][eg * 6];
            float2 v1 = *(const float2*)&Vs[kk][eg * 6 + 2];
            float2 v2 = *(const float2*)&Vs[kk][eg * 6 + 4];
            accA[0] += pA * v0.x; accA[1] += pA * v0.y;
            accA[2] += pA * v1.x; accA[3] += pA * v1.y;
            accA[4] += pA * v2.x; accA[5] += pA * v2.y;
            accB[0] += pB * v0.x; accB[1] += pB * v0.y;
            accB[2] += pB * v1.x; accB[3] += pB * v1.y;
            accB[4] += pB * v2.x; accB[5] += pB * v2.y;
        }
    }

    const float lA = hi ? l_[2] : l_[0];
    const float lB = hi ? l_[3] : l_[1];
    const float iA = 1.0f / lA;
    const float iB = 1.0f / lB;
    const int sA = qt * 64 + 2 * qg;
    float* oA = AO + ((size_t)b * Sc + sA) * DIMc + h * DHc + eg * 6;
    float* oB = oA + DIMc;
    #pragma unroll
    for (int j = 0; j < 6; ++j) {
        oA[j] = accA[j] * iA;
        oB[j] = accB[j] * iB;
    }
}

// ---------------------------------------------------------------------------
// Kernel C: output projection, register-blocked fp32 GEMM (audited, unchanged).
// grid = (12, 64), block = 256.
// ---------------------------------------------------------------------------
__global__ __launch_bounds__(256, 2) void out_proj(
    const float* __restrict__ A, const float* __restrict__ Wp,
    const float* __restrict__ bp, float* __restrict__ out)
{
    const int ct = blockIdx.x;
    const int rt = blockIdx.y;

    __shared__ float Ast[16][132];
    __shared__ float Ws[16][68];

    const int t  = threadIdx.x;
    const int rg = t >> 4;
    const int cg = t & 15;
    const int row0 = rt * 128, col0 = ct * 64;

    float acc[8][4];
    #pragma unroll
    for (int i = 0; i < 8; ++i)
        #pragma unroll
        for (int j = 0; j < 4; ++j) acc[i][j] = 0.f;

    for (int k0 = 0; k0 < DIMc; k0 += 16) {
        __syncthreads();
        #pragma unroll
        for (int i = 0; i < 2; ++i) {
            const int jj = t + i * 256;
            const int r  = jj >> 2;
            const int kc = jj & 3;
            float4 v = *(const float4*)&A[(size_t)(row0 + r) * DIMc + k0 + kc * 4];
            Ast[kc * 4 + 0][r] = v.x;
            Ast[kc * 4 + 1][r] = v.y;
            Ast[kc * 4 + 2][r] = v.z;
            Ast[kc * 4 + 3][r] = v.w;
        }
        {
            const int wr = t >> 4, wc = t & 15;
            *(float4*)&Ws[wr][wc * 4] =
                *(const float4*)&Wp[(size_t)(k0 + wr) * DIMc + col0 + wc * 4];
        }
        __syncthreads();

        #pragma unroll
        for (int kk = 0; kk < 16; ++kk) {
            float4 a0 = *(const float4*)&Ast[kk][rg * 8];
            float4 a1 = *(const float4*)&Ast[kk][rg * 8 + 4];
            float4 w  = *(const float4*)&Ws[kk][cg * 4];
            const float a[8] = {a0.x, a0.y, a0.z, a0.w, a1.x, a1.y, a1.z, a1.w};
            #pragma unroll
            for (int i = 0; i < 8; ++i) {
                acc[i][0] += a[i] * w.x;
                acc[i][1] += a[i] * w.y;
                acc[i][2] += a[i] * w.z;
                acc[i][3] += a[i] * w.w;
            }
        }
    }

    float4 bb = *(const float4*)&bp[col0 + cg * 4];
    #pragma unroll
    for (int i = 0; i < 8; ++i) {
        float4 r = make_float4(acc[i][0] + bb.x, acc[i][1] + bb.y,
                               acc[i][2] + bb.z, acc[i][3] + bb.w);
        *(float4*)&out[(size_t)(row0 + rg * 8 + i) * DIMc + col0 + cg * 4] = r;
    }
}

// ---------------------------------------------------------------------------
extern "C" void kernel_launch(void* const* d_in, const int* in_sizes, int n_in,
                              void* d_out, int out_size, void* d_ws, size_t ws_size,
                              hipStream_t stream)
{
    (void)in_sizes; (void)n_in; (void)out_size; (void)ws_size;

    const float* x  = (const float*)d_in[0];
    const float* Wq = (const float*)d_in[1];
    const float* bq = (const float*)d_in[2];
    const float* Wk = (const float*)d_in[3];
    const float* bk = (const float*)d_in[4];
    const float* Wv = (const float*)d_in[5];
    const float* bv = (const float*)d_in[6];
    const float* Wp = (const float*)d_in[7];
    const float* bp = (const float*)d_in[8];
    float* out = (float*)d_out;
    float* ws  = (float*)d_ws;

    // ws layout (100.7 MB total, same budget as the validated round-0 run):
    //   Q | K | V  ([B,H,S,DH] f32, 25.2 MB each)
    //   AO region  ([B,S,DIM] f32, 25.2 MB) -- time-shared:
    //     phase 1 (before attn): xb bf16 (12.6) | WbT bf16 (3.54) | bcomb f32
    //     phase 2 (attn onward): AO f32
    const size_t QSZ = (size_t)Bc * Hc * Sc * DHc;
    float* Qb = ws;
    float* Kb = ws + QSZ;
    float* Vb = ws + 2 * QSZ;
    float* AO = ws + 3 * QSZ;
    ushort* xb  = (ushort*)AO;
    ushort* WbT = xb + (size_t)NROW * DIMc;           // +6291456 ushorts
    float*  bcomb = (float*)(WbT + (size_t)NQKV * DIMc);

    cvt_x<<<NROW * DIMc / (256 * 4), 256, 0, stream>>>(x, xb);
    cvt_w<<<NQKV * DIMc / 256, 256, 0, stream>>>(Wq, bq, Wk, bk, Wv, bv,
                                                 WbT, bcomb);
    qkv_mfma<<<dim3(NQKV / 128, NROW / 128), 256, 0, stream>>>(
        xb, WbT, bcomb, Qb, Kb, Vb);
    attn_kernel<<<dim3(Sc / 64, Hc, Bc), 256, 0, stream>>>(Qb, Kb, Vb, AO);
    out_proj<<<dim3(12, 64), 256, 0, stream>>>(AO, Wp, bp, out);
}

// Round 10
// 278.373 us; speedup vs baseline: 15.6166x; 2.6596x over previous
//
#include <hip/hip_runtime.h>
#include <math.h>

constexpr int DIMc = 768;
constexpr int Hc   = 16;
constexpr int DHc  = 48;
constexpr int Bc   = 8;
constexpr int Sc   = 1024;
constexpr int NROW = Bc * Sc;                      // 8192
constexpr int NQKV = 3 * Hc * DHc;                 // 2304
constexpr float INV_SCALE = 0.03608439182435161f;  // 1/sqrt(768)

constexpr int PQ = 72;   // attn LDS pitch for Q/K rows (bf16 elems; 48 data+16 zero+8 pad)
constexpr int PT = 72;   // attn LDS pitch for Vt / P rows

typedef short  bf16x8 __attribute__((ext_vector_type(8)));
typedef float  f32x4  __attribute__((ext_vector_type(4)));
typedef ushort u16x8  __attribute__((ext_vector_type(8)));

// RNE float->bf16
__device__ inline ushort f2bf(float f) {
    uint u = __float_as_uint(f);
    return (ushort)((u + 0x7fffu + ((u >> 16) & 1u)) >> 16);
}
// round-half-up float->bf16 (cheap, for P in [0,1])
__device__ inline uint f2bf_hu(float f) {
    return (__float_as_uint(f) + 0x8000u) >> 16;
}

__device__ inline void gload_lds16(const void* g, void* l) {
    __builtin_amdgcn_global_load_lds(
        (const __attribute__((address_space(1))) void*)g,
        (__attribute__((address_space(3))) void*)l, 16, 0, 0);
}

// ---------------------------------------------------------------------------
// cvt_x: x f32 [8192][768] -> xb bf16 (same layout)
// ---------------------------------------------------------------------------
__global__ __launch_bounds__(256) void cvt_x(
    const float* __restrict__ x, ushort* __restrict__ xb)
{
    const int i = (blockIdx.x * 256 + threadIdx.x) * 4;
    float4 v = *(const float4*)&x[i];
    ushort4 o;
    o.x = f2bf(v.x); o.y = f2bf(v.y); o.z = f2bf(v.z); o.w = f2bf(v.w);
    *(ushort4*)&xb[i] = o;
}

// ---------------------------------------------------------------------------
// cvt_w: WbT[n=2304][k=768] bf16 (n = h*144 + m*48 + e) + bcomb[2304] f32
// ---------------------------------------------------------------------------
__global__ __launch_bounds__(256) void cvt_w(
    const float* __restrict__ Wq, const float* __restrict__ bq,
    const float* __restrict__ Wk, const float* __restrict__ bk,
    const float* __restrict__ Wv, const float* __restrict__ bv,
    ushort* __restrict__ WbT, float* __restrict__ bcomb)
{
    const int id = blockIdx.x * 256 + threadIdx.x;
    const int n = id / DIMc;
    const int k = id - n * DIMc;
    const int h = n / 144;
    const int rem = n - h * 144;
    const int m = rem / DHc;
    const int e = rem - m * DHc;
    const float* W = (m == 0) ? Wq : (m == 1) ? Wk : Wv;
    const float* bias = (m == 0) ? bq : (m == 1) ? bk : bv;
    WbT[(size_t)n * DIMc + k] = f2bf(W[((size_t)h * DIMc + k) * DHc + e]);
    if (k == 0) bcomb[n] = bias[h * DHc + e];
}

// ---------------------------------------------------------------------------
// cvt_wp: WpT[n=768][k=768] bf16 from Wp[k][n] f32
// ---------------------------------------------------------------------------
__global__ __launch_bounds__(256) void cvt_wp(
    const float* __restrict__ Wp, ushort* __restrict__ WpT)
{
    const int id = blockIdx.x * 256 + threadIdx.x;
    const int n = id / DIMc;
    const int k = id - n * DIMc;
    WpT[(size_t)n * DIMc + k] = f2bf(Wp[(size_t)k * DIMc + n]);
}

// ---------------------------------------------------------------------------
// Kernel A: fused QKV bf16 MFMA GEMM (m97 structure), 128x128 tile, BK=32.
// Outputs (all bf16): Qb [b][h][s][48] pre-scaled by 1/sqrt(768),
//                     Kb [b][h][s][48],  Vt [b][h][e][s] (transposed).
// grid = (18, 64), block = 256 (4 waves, 2x2).
// ---------------------------------------------------------------------------
__global__ __launch_bounds__(256) void qkv_mfma(
    const ushort* __restrict__ xb, const ushort* __restrict__ WbT,
    const float* __restrict__ bcomb,
    ushort* __restrict__ Qb, ushort* __restrict__ Kb, ushort* __restrict__ Vt)
{
    __shared__ __align__(16) ushort Abuf[128 * 32];
    __shared__ __align__(16) ushort Bbuf[128 * 32];

    const int t    = threadIdx.x;
    const int lane = t & 63;
    const int wid  = t >> 6;
    const int wrow = wid >> 1;
    const int wcol = wid & 1;
    const int l15  = lane & 15;
    const int l16  = lane >> 4;
    const int row0 = blockIdx.y * 128;
    const int col0 = blockIdx.x * 128;

    f32x4 acc[4][4];
    #pragma unroll
    for (int i = 0; i < 4; ++i)
        #pragma unroll
        for (int j = 0; j < 4; ++j)
            acc[i][j] = (f32x4){0.f, 0.f, 0.f, 0.f};

    for (int k0 = 0; k0 < DIMc; k0 += 32) {
        __syncthreads();
        #pragma unroll
        for (int j = 0; j < 2; ++j) {
            const int c = j * 256 + t;
            gload_lds16(xb + (size_t)(row0 + (c >> 2)) * DIMc + k0 + (c & 3) * 8,
                        &Abuf[(size_t)c * 8]);
            gload_lds16(WbT + (size_t)(col0 + (c >> 2)) * DIMc + k0 + (c & 3) * 8,
                        &Bbuf[(size_t)c * 8]);
        }
        __syncthreads();

        bf16x8 af[4], bfr[4];
        #pragma unroll
        for (int i = 0; i < 4; ++i) {
            af[i]  = *(const bf16x8*)((const char*)Abuf +
                       ((wrow * 64 + i * 16 + l15) * 64 + l16 * 16));
            bfr[i] = *(const bf16x8*)((const char*)Bbuf +
                       ((wcol * 64 + i * 16 + l15) * 64 + l16 * 16));
        }
        #pragma unroll
        for (int i = 0; i < 4; ++i)
            #pragma unroll
            for (int j = 0; j < 4; ++j)
                acc[i][j] = __builtin_amdgcn_mfma_f32_16x16x32_bf16(
                    af[i], bfr[j], acc[i][j], 0, 0, 0);
    }

    // epilogue: C/D layout col=lane&15, row=(lane>>4)*4+reg
    const int b_ = (row0 >> 10);   // whole 128-row tile lies in one b
    #pragma unroll
    for (int i = 0; i < 4; ++i) {
        const int s0 = (row0 & 1023) + wrow * 64 + i * 16 + l16 * 4;
        #pragma unroll
        for (int j = 0; j < 4; ++j) {
            const int n0 = col0 + wcol * 64 + j * 16;   // wave-uniform
            const int h = n0 / 144;
            const int rem = n0 - h * 144;
            const int m = rem / DHc;
            const int e = (rem - m * DHc) + l15;
            const float bias = bcomb[n0 + l15];
            if (m == 2) {
                // Vt[((b*H+h)*48+e)*1024 + s0..+3]
                ushort4 w;
                w.x = f2bf(acc[i][j][0] + bias);
                w.y = f2bf(acc[i][j][1] + bias);
                w.z = f2bf(acc[i][j][2] + bias);
                w.w = f2bf(acc[i][j][3] + bias);
                *(ushort4*)&Vt[((size_t)(b_ * Hc + h) * DHc + e) * Sc + s0] = w;
            } else {
                ushort* O = (m == 0) ? Qb : Kb;
                const float sc = (m == 0) ? INV_SCALE : 1.0f;
                #pragma unroll
                for (int r = 0; r < 4; ++r)
                    O[((size_t)(b_ * Hc + h) * Sc + s0 + r) * DHc + e] =
                        f2bf((acc[i][j][r] + bias) * sc);
            }
        }
    }
}

// ---------------------------------------------------------------------------
// Kernel B: flash attention, bf16 MFMA.
// grid = (16, 16, 8) = (q-tile, h, b); block = 256 (4 waves x 16 q-rows).
// Swapped QK^T: S^T = mfma(K_frag, Q_frag) -> lane holds 16 scores of its own
// q-row (q = lane&15); softmax reduce = 2 shfl_xor (16, 32). P packed bf16 to
// per-wave LDS, PV reads it as the A-frag; V^T staged from global Vt.
// dh padded 48->64 with zeroed LDS columns.
// ---------------------------------------------------------------------------
__global__ __launch_bounds__(256) void attn_mfma(
    const ushort* __restrict__ Qg, const ushort* __restrict__ Kg,
    const ushort* __restrict__ Vtg, ushort* __restrict__ AOb)
{
    __shared__ __align__(16) ushort Qs[64 * PQ];
    __shared__ __align__(16) ushort Ks[64 * PQ];
    __shared__ __align__(16) ushort Vts[48 * PT];
    __shared__ __align__(16) ushort Ps[4][16 * PT];

    const int t    = threadIdx.x;
    const int lane = t & 63;
    const int wid  = t >> 6;
    const int l15  = lane & 15;
    const int l16  = lane >> 4;
    const int q0   = blockIdx.x * 64;
    const int h    = blockIdx.y;
    const int b    = blockIdx.z;

    const size_t bh = (size_t)(b * Hc + h);
    const ushort* Qp = Qg + (bh * Sc + q0) * DHc;
    const ushort* Kp = Kg + bh * Sc * DHc;
    const ushort* Vp = Vtg + bh * DHc * Sc;    // [e][s]

    // zero the dh pad (cols 48..63) of Qs, Ks — staging never rewrites it
    for (int idx = t; idx < 64 * 16; idx += 256) {
        const int r = idx >> 4, e = 48 + (idx & 15);
        Qs[r * PQ + e] = 0;
        Ks[r * PQ + e] = 0;
    }
    // stage Q tile: 64 rows x 48 elems = 384 16B-chunks
    for (int c = t; c < 384; c += 256) {
        const int r = c / 6, o = (c % 6) * 8;
        *(u16x8*)&Qs[r * PQ + o] = *(const u16x8*)&Qp[r * DHc + o];
    }
    __syncthreads();

    // wave-resident Q frags (B-operand): Q[q=l15][dh-chunk]
    const ushort* qrow = &Qs[(wid * 16 + l15) * PQ];
    const bf16x8 qf0 = *(const bf16x8*)&qrow[l16 * 8];
    const bf16x8 qf1 = *(const bf16x8*)&qrow[32 + l16 * 8];

    float m_st = -3.0e38f, l_st = 0.f;
    f32x4 o_acc[3];
    #pragma unroll
    for (int ef = 0; ef < 3; ++ef) o_acc[ef] = (f32x4){0.f, 0.f, 0.f, 0.f};

    for (int t0 = 0; t0 < Sc; t0 += 64) {
        __syncthreads();   // previous tile's readers done
        // stage K (64x48) + V^T (48x64): 768 chunks, 3/thread
        for (int c = t; c < 768; c += 256) {
            if (c < 384) {
                const int r = c / 6, o = (c % 6) * 8;
                *(u16x8*)&Ks[r * PQ + o] = *(const u16x8*)&Kp[(t0 + r) * DHc + o];
            } else {
                const int c2 = c - 384;
                const int r = c2 >> 3, o = (c2 & 7) * 8;
                *(u16x8*)&Vts[r * PT + o] = *(const u16x8*)&Vp[(size_t)r * Sc + t0 + o];
            }
        }
        __syncthreads();

        // S^T[k'][q]: 4 M-frags x 2 dh-chunks
        f32x4 s[4];
        #pragma unroll
        for (int f = 0; f < 4; ++f) {
            const ushort* krow = &Ks[(f * 16 + l15) * PQ];
            const bf16x8 ka = *(const bf16x8*)&krow[l16 * 8];
            const bf16x8 kb = *(const bf16x8*)&krow[32 + l16 * 8];
            s[f] = __builtin_amdgcn_mfma_f32_16x16x32_bf16(
                ka, qf0, (f32x4){0.f, 0.f, 0.f, 0.f}, 0, 0, 0);
            s[f] = __builtin_amdgcn_mfma_f32_16x16x32_bf16(
                kb, qf1, s[f], 0, 0, 0);
        }

        // online softmax: lane owns q=l15; its 16 scores live in s[f][r]
        float mx = s[0][0];
        #pragma unroll
        for (int f = 0; f < 4; ++f)
            #pragma unroll
            for (int r = 0; r < 4; ++r) mx = fmaxf(mx, s[f][r]);
        mx = fmaxf(mx, __shfl_xor(mx, 16));
        mx = fmaxf(mx, __shfl_xor(mx, 32));
        const float mnew = fmaxf(m_st, mx);
        const float corr = __expf(m_st - mnew);
        float ssum = 0.f;
        #pragma unroll
        for (int f = 0; f < 4; ++f)
            #pragma unroll
            for (int r = 0; r < 4; ++r) {
                const float p = __expf(s[f][r] - mnew);
                s[f][r] = p;
                ssum += p;
            }
        ssum += __shfl_xor(ssum, 16);
        ssum += __shfl_xor(ssum, 32);
        l_st = l_st * corr + ssum;
        m_st = mnew;

        // P -> per-wave LDS tile [q][k'] bf16 (pitch 72)
        #pragma unroll
        for (int f = 0; f < 4; ++f) {
            const uint p01 = f2bf_hu(s[f][0]) | (f2bf_hu(s[f][1]) << 16);
            const uint p23 = f2bf_hu(s[f][2]) | (f2bf_hu(s[f][3]) << 16);
            ushort* dst = &Ps[wid][l15 * PT + f * 16 + l16 * 4];
            *(uint*)&dst[0] = p01;
            *(uint*)&dst[2] = p23;
        }

        // rescale O accumulators: rows q = l16*4+r, state lives in lane q
        float corr_r[4];
        #pragma unroll
        for (int r = 0; r < 4; ++r) corr_r[r] = __shfl(corr, l16 * 4 + r);
        #pragma unroll
        for (int ef = 0; ef < 3; ++ef)
            #pragma unroll
            for (int r = 0; r < 4; ++r) o_acc[ef][r] *= corr_r[r];

        // PV: O[q][e] += P[q][k'] V[k'][e]
        #pragma unroll
        for (int ch = 0; ch < 2; ++ch) {
            const bf16x8 pf = *(const bf16x8*)&Ps[wid][l15 * PT + ch * 32 + l16 * 8];
            #pragma unroll
            for (int ef = 0; ef < 3; ++ef) {
                const bf16x8 vf = *(const bf16x8*)
                    &Vts[(ef * 16 + l15) * PT + ch * 32 + l16 * 8];
                o_acc[ef] = __builtin_amdgcn_mfma_f32_16x16x32_bf16(
                    pf, vf, o_acc[ef], 0, 0, 0);
            }
        }
    }

    // finalize: divide by l (per q-row, shfl'd), write AO bf16 [b][s][h*48+e]
    float inv_r[4];
    #pragma unroll
    for (int r = 0; r < 4; ++r) inv_r[r] = 1.0f / __shfl(l_st, l16 * 4 + r);
    #pragma unroll
    for (int ef = 0; ef < 3; ++ef)
        #pragma unroll
        for (int r = 0; r < 4; ++r) {
            const int s_ = q0 + wid * 16 + l16 * 4 + r;
            AOb[((size_t)b * Sc + s_) * DIMc + h * DHc + ef * 16 + l15] =
                f2bf(o_acc[ef][r] * inv_r[r]);
        }
}

// ---------------------------------------------------------------------------
// Kernel C: output projection bf16 MFMA GEMM. out = AOb @ WpT^T + bp (f32 out)
// grid = (6, 64), block = 256.
// ---------------------------------------------------------------------------
__global__ __launch_bounds__(256) void outp_mfma(
    const ushort* __restrict__ A, const ushort* __restrict__ BT,
    const float* __restrict__ bp, float* __restrict__ out)
{
    __shared__ __align__(16) ushort Abuf[128 * 32];
    __shared__ __align__(16) ushort Bbuf[128 * 32];

    const int t    = threadIdx.x;
    const int lane = t & 63;
    const int wid  = t >> 6;
    const int wrow = wid >> 1;
    const int wcol = wid & 1;
    const int l15  = lane & 15;
    const int l16  = lane >> 4;
    const int row0 = blockIdx.y * 128;
    const int col0 = blockIdx.x * 128;

    f32x4 acc[4][4];
    #pragma unroll
    for (int i = 0; i < 4; ++i)
        #pragma unroll
        for (int j = 0; j < 4; ++j)
            acc[i][j] = (f32x4){0.f, 0.f, 0.f, 0.f};

    for (int k0 = 0; k0 < DIMc; k0 += 32) {
        __syncthreads();
        #pragma unroll
        for (int j = 0; j < 2; ++j) {
            const int c = j * 256 + t;
            gload_lds16(A + (size_t)(row0 + (c >> 2)) * DIMc + k0 + (c & 3) * 8,
                        &Abuf[(size_t)c * 8]);
            gload_lds16(BT + (size_t)(col0 + (c >> 2)) * DIMc + k0 + (c & 3) * 8,
                        &Bbuf[(size_t)c * 8]);
        }
        __syncthreads();

        bf16x8 af[4], bfr[4];
        #pragma unroll
        for (int i = 0; i < 4; ++i) {
            af[i]  = *(const bf16x8*)((const char*)Abuf +
                       ((wrow * 64 + i * 16 + l15) * 64 + l16 * 16));
            bfr[i] = *(const bf16x8*)((const char*)Bbuf +
                       ((wcol * 64 + i * 16 + l15) * 64 + l16 * 16));
        }
        #pragma unroll
        for (int i = 0; i < 4; ++i)
            #pragma unroll
            for (int j = 0; j < 4; ++j)
                acc[i][j] = __builtin_amdgcn_mfma_f32_16x16x32_bf16(
                    af[i], bfr[j], acc[i][j], 0, 0, 0);
    }

    #pragma unroll
    for (int i = 0; i < 4; ++i) {
        const int grow0 = row0 + wrow * 64 + i * 16 + l16 * 4;
        #pragma unroll
        for (int j = 0; j < 4; ++j) {
            const int n = col0 + wcol * 64 + j * 16 + l15;
            const float bias = bp[n];
            #pragma unroll
            for (int r = 0; r < 4; ++r)
                out[(size_t)(grow0 + r) * DIMc + n] = acc[i][j][r] + bias;
        }
    }
}

// ---------------------------------------------------------------------------
extern "C" void kernel_launch(void* const* d_in, const int* in_sizes, int n_in,
                              void* d_out, int out_size, void* d_ws, size_t ws_size,
                              hipStream_t stream)
{
    (void)in_sizes; (void)n_in; (void)out_size; (void)ws_size;

    const float* x  = (const float*)d_in[0];
    const float* Wq = (const float*)d_in[1];
    const float* bq = (const float*)d_in[2];
    const float* Wk = (const float*)d_in[3];
    const float* bk = (const float*)d_in[4];
    const float* Wv = (const float*)d_in[5];
    const float* bv = (const float*)d_in[6];
    const float* Wp = (const float*)d_in[7];
    const float* bp = (const float*)d_in[8];
    float* out = (float*)d_out;

    // ws layout (bf16 regions, all 16B aligned; ~68 MB total, under the
    // 100.7 MB budget validated in rounds 1/5):
    ushort* w = (ushort*)d_ws;
    ushort* xb   = w;  w += (size_t)NROW * DIMc;    // 6291456
    ushort* WbT  = w;  w += (size_t)NQKV * DIMc;    // 1769472
    ushort* WpT  = w;  w += (size_t)DIMc * DIMc;    // 589824
    ushort* Qb   = w;  w += (size_t)Bc * Hc * Sc * DHc;  // 6291456
    ushort* Kb   = w;  w += (size_t)Bc * Hc * Sc * DHc;
    ushort* Vt   = w;  w += (size_t)Bc * Hc * Sc * DHc;
    ushort* AOb  = w;  w += (size_t)NROW * DIMc;
    float*  bcomb = (float*)w;

    cvt_x<<<NROW * DIMc / 1024, 256, 0, stream>>>(x, xb);
    cvt_w<<<NQKV * DIMc / 256, 256, 0, stream>>>(Wq, bq, Wk, bk, Wv, bv,
                                                 WbT, bcomb);
    cvt_wp<<<DIMc * DIMc / 256, 256, 0, stream>>>(Wp, WpT);
    qkv_mfma<<<dim3(NQKV / 128, NROW / 128), 256, 0, stream>>>(
        xb, WbT, bcomb, Qb, Kb, Vt);
    attn_mfma<<<dim3(Sc / 64, Hc, Bc), 256, 0, stream>>>(Qb, Kb, Vt, AOb);
    outp_mfma<<<dim3(DIMc / 128, NROW / 128), 256, 0, stream>>>(
        AOb, WpT, bp, out);
}